// Round 4
// baseline (571.412 us; speedup 1.0000x reference)
//
#include <hip/hip_runtime.h>
#include <stdint.h>

#define N_TOK 2048
#define H_DIM 1024
#define F_DIM 2816
#define N_EXP 8
#define NSLOT (N_TOK * 2)

#define BK 64
#define KSPLIT 2
#define KHALF (F_DIM / KSPLIT)   // 1408

#define NU_W (N_EXP * F_DIM * H_DIM / 8)  // 8-float units per weight tensor = 2883584 (even)

typedef __attribute__((ext_vector_type(8))) short bf16x8;
typedef __attribute__((ext_vector_type(4))) float f32x4;

typedef __attribute__((address_space(1))) unsigned int gu32;
typedef __attribute__((address_space(3))) unsigned int lu32;

static __device__ __forceinline__ unsigned short f2bf(float f) {
    union { float f; unsigned u; } v; v.f = f;
    unsigned r = v.u + 0x7fffu + ((v.u >> 16) & 1u);   // round-to-nearest-even
    return (unsigned short)(r >> 16);
}

// async 16B/lane global->LDS; LDS dest must be wave-uniform base (lane*16 implicit)
static __device__ __forceinline__ void gload16(const unsigned short* g, unsigned short* l) {
    __builtin_amdgcn_global_load_lds((const gu32*)g, (lu32*)l, 16, 0, 0);
}

// T1: bijective chunked XCD swizzle over (bx,by); requires nwg % 8 == 0.
// XCD k (= hw id % 8) gets logical tiles [k*cpx, (k+1)*cpx) -> contiguous
// x-tiles (same A-panel) share one XCD's L2.
static __device__ __forceinline__ void xcd_swz(int gx, int nwg, int& bx, int& by) {
    int f = bx + gx * by;
    const int cpx = nwg >> 3;
    f = (f & 7) * cpx + (f >> 3);
    bx = f % gx; by = f / gx;
}

// ---------------- Convert: fp32 -> bf16 for w1, w2 ----------------------------
static __device__ __forceinline__ void conv8(const float* __restrict__ src,
                                             unsigned short* __restrict__ dst, long k)
{
    const float4 a = *(const float4*)(src + k * 8);
    const float4 b = *(const float4*)(src + k * 8 + 4);
    uint4 o;
    o.x = (unsigned)f2bf(a.x) | ((unsigned)f2bf(a.y) << 16);
    o.y = (unsigned)f2bf(a.z) | ((unsigned)f2bf(a.w) << 16);
    o.z = (unsigned)f2bf(b.x) | ((unsigned)f2bf(b.y) << 16);
    o.w = (unsigned)f2bf(b.z) | ((unsigned)f2bf(b.w) << 16);
    *(uint4*)(dst + k * 8) = o;
}

__global__ __launch_bounds__(256) void convert_w_kernel(
    const float* __restrict__ w1, const float* __restrict__ w2,
    unsigned short* __restrict__ w1_bf, unsigned short* __restrict__ w2_bf)
{
    const long total = 2L * NU_W;
    long u = ((long)blockIdx.x * 256 + threadIdx.x) * 2;   // 2 contiguous units = 64B read
    const long stride = (long)gridDim.x * 256 * 2;
    for (; u < total; u += stride) {
        // NU_W is even and u is even, so (u, u+1) never straddle the tensor boundary
        const float* src = (u < NU_W) ? w1 : w2;
        unsigned short* dst = (u < NU_W) ? w1_bf : w2_bf;
        const long k = (u < NU_W) ? u : u - NU_W;
        conv8(src, dst, k);
        conv8(src, dst, k + 1);
    }
}

// ---------------- Router: 1 wave per token; also emits x_bf -------------------
__global__ __launch_bounds__(256) void router_kernel(
    const float* __restrict__ x, const float* __restrict__ gate_w,
    int* __restrict__ counts, int* __restrict__ row_token, float* __restrict__ row_weight,
    int* __restrict__ slot_e, int* __restrict__ slot_pos,
    unsigned short* __restrict__ x_bf)
{
    __shared__ float gsm[N_EXP * H_DIM];
    for (int i = threadIdx.x; i < N_EXP * H_DIM / 4; i += 256)
        ((float4*)gsm)[i] = ((const float4*)gate_w)[i];
    __syncthreads();

    const int wave = threadIdx.x >> 6;
    const int lane = threadIdx.x & 63;
    const int n = blockIdx.x * 4 + wave;
    if (n >= N_TOK) return;

    const float4* xrow = (const float4*)(x + (size_t)n * H_DIM);
    float4 xv[4];
#pragma unroll
    for (int i = 0; i < 4; i++) xv[i] = xrow[lane + 64 * i];

    // fused x -> bf16 (saves a pass in the convert kernel)
#pragma unroll
    for (int i = 0; i < 4; i++) {
        ushort4 b;
        b.x = f2bf(xv[i].x); b.y = f2bf(xv[i].y); b.z = f2bf(xv[i].z); b.w = f2bf(xv[i].w);
        *(ushort4*)(x_bf + (size_t)n * H_DIM + (lane + 64 * i) * 4) = b;
    }

    float logit[N_EXP];
#pragma unroll
    for (int e = 0; e < N_EXP; e++) {
        float p = 0.f;
#pragma unroll
        for (int i = 0; i < 4; i++) {
            const float4 g = ((const float4*)gsm)[e * 256 + lane + 64 * i];
            p += xv[i].x * g.x + xv[i].y * g.y + xv[i].z * g.z + xv[i].w * g.w;
        }
#pragma unroll
        for (int s = 32; s > 0; s >>= 1) p += __shfl_xor(p, s, 64);
        logit[e] = p;
    }

    if (lane == 0) {
        int e0 = 0; float l0 = logit[0];
#pragma unroll
        for (int e = 1; e < N_EXP; e++) if (logit[e] > l0) { l0 = logit[e]; e0 = e; }
        int e1 = -1; float l1 = -3.4e38f;
#pragma unroll
        for (int e = 0; e < N_EXP; e++) if (e != e0 && logit[e] > l1) { l1 = logit[e]; e1 = e; }
        float w0 = 1.f / (1.f + __expf(l1 - l0));
        float w1 = 1.f - w0;
        int p0 = atomicAdd(&counts[e0], 1);
        int p1 = atomicAdd(&counts[e1], 1);
        row_token[e0 * N_TOK + p0] = n;  row_weight[e0 * N_TOK + p0] = w0;
        row_token[e1 * N_TOK + p1] = n;  row_weight[e1 * N_TOK + p1] = w1;
        slot_e[n * 2 + 0] = e0;  slot_pos[n * 2 + 0] = p0;
        slot_e[n * 2 + 1] = e1;  slot_pos[n * 2 + 1] = p1;
    }
}

// ---------------- Scan: exclusive prefix over 8 counts ----------------
__global__ void scan_kernel(const int* __restrict__ counts, int* __restrict__ offsets)
{
    if (threadIdx.x == 0 && blockIdx.x == 0) {
        int acc = 0;
        for (int e = 0; e < N_EXP; e++) { offsets[e] = acc; acc += counts[e]; }
    }
}

// ---------------- Up GEMM (grouped, m97 structure + T1): act = silu(X @ w1^T) --
__global__ __launch_bounds__(256) void up_gemm_kernel(
    const unsigned short* __restrict__ x_bf, const unsigned short* __restrict__ w1_bf,
    const int* __restrict__ counts, const int* __restrict__ offsets,
    const int* __restrict__ row_token,
    unsigned short* __restrict__ act)
{
    const int e = blockIdx.z;
    const int cnt = counts[e];
    int fTile = blockIdx.x, mTile = blockIdx.y;
    xcd_swz(F_DIM / 128, (F_DIM / 128) * (N_TOK / 128), fTile, mTile);   // nwg=352, %8==0
    if (mTile * 128 >= cnt) return;
    const int off = offsets[e];

    __shared__ __align__(16) unsigned short As[128 * 64];
    __shared__ __align__(16) unsigned short Bs[128 * 64];

    const int tid = threadIdx.x;
    const int lane = tid & 63;
    const int wave = tid >> 6;
    const int wm = (wave >> 1) * 64, wn = (wave & 1) * 64;

    const unsigned short* aSrc[4];
    const unsigned short* bSrc[4];
#pragma unroll
    for (int j = 0; j < 4; j++) {
        const int row_local = wave * 32 + j * 8 + (lane >> 3);
        const int pos = mTile * 128 + row_local;
        const int tok = row_token[e * N_TOK + min(pos, cnt - 1)];
        aSrc[j] = x_bf + (size_t)tok * H_DIM + (lane & 7) * 8;
        bSrc[j] = w1_bf + ((size_t)e * F_DIM + fTile * 128 + row_local) * H_DIM + (lane & 7) * 8;
    }

    f32x4 acc[4][4];
#pragma unroll
    for (int i = 0; i < 4; i++)
#pragma unroll
        for (int j = 0; j < 4; j++) acc[i][j] = (f32x4)(0.f);

    const int NKT = H_DIM / BK;   // 16
    for (int kt = 0; kt < NKT; kt++) {
        const int koff = kt * BK;
#pragma unroll
        for (int j = 0; j < 4; j++) {
            gload16(aSrc[j] + koff, As + (wave * 4 + j) * 512);
            gload16(bSrc[j] + koff, Bs + (wave * 4 + j) * 512);
        }
        __syncthreads();
#pragma unroll
        for (int kk = 0; kk < BK / 32; kk++) {
            const int kloc = kk * 32 + (lane >> 4) * 8;
            bf16x8 af[4], bfr[4];
#pragma unroll
            for (int i = 0; i < 4; i++)
                af[i] = *(const bf16x8*)(As + (wm + i * 16 + (lane & 15)) * 64 + kloc);
#pragma unroll
            for (int i = 0; i < 4; i++)
                bfr[i] = *(const bf16x8*)(Bs + (wn + i * 16 + (lane & 15)) * 64 + kloc);
#pragma unroll
            for (int i = 0; i < 4; i++)
#pragma unroll
                for (int j = 0; j < 4; j++)
                    acc[i][j] = __builtin_amdgcn_mfma_f32_16x16x32_bf16(af[i], bfr[j], acc[i][j], 0, 0, 0);
        }
        __syncthreads();
    }

    // epilogue: silu + bf16 store (C/D layout: col=lane&15, row=(lane>>4)*4+reg)
#pragma unroll
    for (int i = 0; i < 4; i++) {
        const int mrow = wm + i * 16 + ((lane >> 4) << 2);
#pragma unroll
        for (int r = 0; r < 4; r++) {
            const int m = mTile * 128 + mrow + r;
            if (m < cnt) {
#pragma unroll
                for (int j = 0; j < 4; j++) {
                    float v = acc[i][j][r];
                    float s = v / (1.f + __expf(-v));
                    int col = fTile * 128 + wn + j * 16 + (lane & 15);
                    act[(size_t)(off + m) * F_DIM + col] = f2bf(s);
                }
            }
        }
    }
}

// ---------------- Down GEMM (grouped, split-K=2, m97 structure + T1) ----------
__global__ __launch_bounds__(256) void down_gemm_kernel(
    const unsigned short* __restrict__ act, const unsigned short* __restrict__ w2_bf,
    const int* __restrict__ counts, const int* __restrict__ offsets,
    const float* __restrict__ row_weight,
    float* __restrict__ out_partial)   // [KSPLIT][NSLOT][H_DIM]
{
    const int e  = blockIdx.z & (N_EXP - 1);
    const int ks = blockIdx.z >> 3;
    const int cnt = counts[e];
    int hTile = blockIdx.x, mTile = blockIdx.y;
    xcd_swz(H_DIM / 128, (H_DIM / 128) * (N_TOK / 128), hTile, mTile);   // nwg=128, %8==0
    if (mTile * 128 >= cnt) return;
    const int off = offsets[e];
    const int kbase = ks * KHALF;

    __shared__ __align__(16) unsigned short As[128 * 64];
    __shared__ __align__(16) unsigned short Bs[128 * 64];

    const int tid = threadIdx.x;
    const int lane = tid & 63;
    const int wave = tid >> 6;
    const int wm = (wave >> 1) * 64, wn = (wave & 1) * 64;

    const unsigned short* aSrc[4];
    const unsigned short* bSrc[4];
#pragma unroll
    for (int j = 0; j < 4; j++) {
        const int row_local = wave * 32 + j * 8 + (lane >> 3);
        const int slot = off + min(mTile * 128 + row_local, cnt - 1);
        aSrc[j] = act + (size_t)slot * F_DIM + kbase + (lane & 7) * 8;
        bSrc[j] = w2_bf + ((size_t)e * H_DIM + hTile * 128 + row_local) * F_DIM + kbase + (lane & 7) * 8;
    }

    f32x4 acc[4][4];
#pragma unroll
    for (int i = 0; i < 4; i++)
#pragma unroll
        for (int j = 0; j < 4; j++) acc[i][j] = (f32x4)(0.f);

    const int NKT = KHALF / BK;   // 22
    for (int kt = 0; kt < NKT; kt++) {
        const int koff = kt * BK;
#pragma unroll
        for (int j = 0; j < 4; j++) {
            gload16(aSrc[j] + koff, As + (wave * 4 + j) * 512);
            gload16(bSrc[j] + koff, Bs + (wave * 4 + j) * 512);
        }
        __syncthreads();
#pragma unroll
        for (int kk = 0; kk < BK / 32; kk++) {
            const int kloc = kk * 32 + (lane >> 4) * 8;
            bf16x8 af[4], bfr[4];
#pragma unroll
            for (int i = 0; i < 4; i++)
                af[i] = *(const bf16x8*)(As + (wm + i * 16 + (lane & 15)) * 64 + kloc);
#pragma unroll
            for (int i = 0; i < 4; i++)
                bfr[i] = *(const bf16x8*)(Bs + (wn + i * 16 + (lane & 15)) * 64 + kloc);
#pragma unroll
            for (int i = 0; i < 4; i++)
#pragma unroll
                for (int j = 0; j < 4; j++)
                    acc[i][j] = __builtin_amdgcn_mfma_f32_16x16x32_bf16(af[i], bfr[j], acc[i][j], 0, 0, 0);
        }
        __syncthreads();
    }

    float* obase = out_partial + (size_t)ks * NSLOT * H_DIM;
#pragma unroll
    for (int i = 0; i < 4; i++) {
        const int mrow = wm + i * 16 + ((lane >> 4) << 2);
#pragma unroll
        for (int r = 0; r < 4; r++) {
            const int m = mTile * 128 + mrow + r;
            if (m < cnt) {
                const float w = row_weight[e * N_TOK + m];
#pragma unroll
                for (int j = 0; j < 4; j++) {
                    int col = hTile * 128 + wn + j * 16 + (lane & 15);
                    obase[(size_t)(off + m) * H_DIM + col] = w * acc[i][j][r];
                }
            }
        }
    }
}

// ---------------- Combine: y[n] = sum over 2 slots x 2 K-splits ---------------
__global__ __launch_bounds__(256) void combine_kernel(
    const float* __restrict__ out_partial, const int* __restrict__ offsets,
    const int* __restrict__ slot_e, const int* __restrict__ slot_pos,
    float* __restrict__ out)
{
    const int n = blockIdx.x;
    const int r0 = offsets[slot_e[n * 2 + 0]] + slot_pos[n * 2 + 0];
    const int r1 = offsets[slot_e[n * 2 + 1]] + slot_pos[n * 2 + 1];
    const int t = threadIdx.x;
    const float* p0 = out_partial;
    const float* p1 = out_partial + (size_t)NSLOT * H_DIM;
    const float4 a = *(const float4*)(p0 + (size_t)r0 * H_DIM + t * 4);
    const float4 b = *(const float4*)(p1 + (size_t)r0 * H_DIM + t * 4);
    const float4 c = *(const float4*)(p0 + (size_t)r1 * H_DIM + t * 4);
    const float4 d = *(const float4*)(p1 + (size_t)r1 * H_DIM + t * 4);
    float4 s;
    s.x = (a.x + b.x) + (c.x + d.x);
    s.y = (a.y + b.y) + (c.y + d.y);
    s.z = (a.z + b.z) + (c.z + d.z);
    s.w = (a.w + b.w) + (c.w + d.w);
    *(float4*)(out + (size_t)n * H_DIM + t * 4) = s;
}

extern "C" void kernel_launch(void* const* d_in, const int* in_sizes, int n_in,
                              void* d_out, int out_size, void* d_ws, size_t ws_size,
                              hipStream_t stream) {
    const float* x      = (const float*)d_in[0];
    const float* gate_w = (const float*)d_in[1];
    const float* w1     = (const float*)d_in[2];
    const float* w2     = (const float*)d_in[3];
    float* out = (float*)d_out;

    char* ws = (char*)d_ws;
    size_t o = 0;
    auto alloc = [&](size_t bytes) -> void* {
        void* p = ws + o;
        o = (o + bytes + 255) & ~(size_t)255;
        return p;
    };
    int*   counts     = (int*)  alloc(N_EXP * sizeof(int));
    int*   offsets    = (int*)  alloc(N_EXP * sizeof(int));
    int*   row_token  = (int*)  alloc((size_t)N_EXP * N_TOK * sizeof(int));
    float* row_weight = (float*)alloc((size_t)N_EXP * N_TOK * sizeof(float));
    int*   slot_e     = (int*)  alloc((size_t)N_TOK * 2 * sizeof(int));
    int*   slot_pos   = (int*)  alloc((size_t)N_TOK * 2 * sizeof(int));
    unsigned short* act = (unsigned short*)alloc((size_t)NSLOT * F_DIM * sizeof(unsigned short));
    float* out_partial = (float*)alloc((size_t)KSPLIT * NSLOT * H_DIM * sizeof(float));
    unsigned short* x_bf  = (unsigned short*)alloc((size_t)N_TOK * H_DIM * sizeof(unsigned short));
    unsigned short* w1_bf = (unsigned short*)alloc((size_t)N_EXP * F_DIM * H_DIM * sizeof(unsigned short));
    unsigned short* w2_bf = (unsigned short*)alloc((size_t)N_EXP * H_DIM * F_DIM * sizeof(unsigned short));

    hipMemsetAsync(counts, 0, N_EXP * sizeof(int), stream);

    router_kernel<<<N_TOK / 4, 256, 0, stream>>>(x, gate_w, counts, row_token, row_weight, slot_e, slot_pos, x_bf);
    scan_kernel<<<1, 64, 0, stream>>>(counts, offsets);
    convert_w_kernel<<<4096, 256, 0, stream>>>(w1, w2, w1_bf, w2_bf);
    up_gemm_kernel<<<dim3(F_DIM / 128, N_TOK / 128, N_EXP), 256, 0, stream>>>(
        x_bf, w1_bf, counts, offsets, row_token, act);
    down_gemm_kernel<<<dim3(H_DIM / 128, N_TOK / 128, N_EXP * KSPLIT), 256, 0, stream>>>(
        act, w2_bf, counts, offsets, row_weight, out_partial);
    combine_kernel<<<N_TOK, 256, 0, stream>>>(out_partial, offsets, slot_e, slot_pos, out);
}

// Round 5
// 397.871 us; speedup vs baseline: 1.4362x; 1.4362x over previous
//
#include <hip/hip_runtime.h>
#include <stdint.h>

#define N_TOK 2048
#define H_DIM 1024
#define F_DIM 2816
#define N_EXP 8
#define NSLOT (N_TOK * 2)

#define BK 64
#define KSPLIT 2
#define KHALF (F_DIM / KSPLIT)   // 1408
#define MAX_TILES 40             // sum_e ceil(cnt_e/128) <= 32 + 7 remainder tiles

#define NU_W (N_EXP * F_DIM * H_DIM / 8)  // 8-float units per weight tensor (even)

typedef __attribute__((ext_vector_type(8))) short bf16x8;
typedef __attribute__((ext_vector_type(4))) float f32x4;

typedef __attribute__((address_space(1))) unsigned int gu32;
typedef __attribute__((address_space(3))) unsigned int lu32;

static __device__ __forceinline__ unsigned short f2bf(float f) {
    union { float f; unsigned u; } v; v.f = f;
    unsigned r = v.u + 0x7fffu + ((v.u >> 16) & 1u);   // round-to-nearest-even
    return (unsigned short)(r >> 16);
}

// async 16B/lane global->LDS; LDS dest must be wave-uniform base (lane*16 implicit)
static __device__ __forceinline__ void gload16(const unsigned short* g, unsigned short* l) {
    __builtin_amdgcn_global_load_lds((const gu32*)g, (lu32*)l, 16, 0, 0);
}

// ---------------- Convert: fp32 -> bf16 for w1, w2 ----------------------------
static __device__ __forceinline__ void conv8(const float* __restrict__ src,
                                             unsigned short* __restrict__ dst, long k)
{
    const float4 a = *(const float4*)(src + k * 8);
    const float4 b = *(const float4*)(src + k * 8 + 4);
    uint4 o;
    o.x = (unsigned)f2bf(a.x) | ((unsigned)f2bf(a.y) << 16);
    o.y = (unsigned)f2bf(a.z) | ((unsigned)f2bf(a.w) << 16);
    o.z = (unsigned)f2bf(b.x) | ((unsigned)f2bf(b.y) << 16);
    o.w = (unsigned)f2bf(b.z) | ((unsigned)f2bf(b.w) << 16);
    *(uint4*)(dst + k * 8) = o;
}

__global__ __launch_bounds__(256) void convert_w_kernel(
    const float* __restrict__ w1, const float* __restrict__ w2,
    unsigned short* __restrict__ w1_bf, unsigned short* __restrict__ w2_bf)
{
    const long total = 2L * NU_W;
    long u = ((long)blockIdx.x * 256 + threadIdx.x) * 2;   // 2 contiguous units = 64B read
    const long stride = (long)gridDim.x * 256 * 2;
    for (; u < total; u += stride) {
        // NU_W is even and u is even, so (u, u+1) never straddle the tensor boundary
        const float* src = (u < NU_W) ? w1 : w2;
        unsigned short* dst = (u < NU_W) ? w1_bf : w2_bf;
        const long k = (u < NU_W) ? u : u - NU_W;
        conv8(src, dst, k);
        conv8(src, dst, k + 1);
    }
}

// ---------------- Router: 1 wave per token; also emits x_bf -------------------
__global__ __launch_bounds__(256) void router_kernel(
    const float* __restrict__ x, const float* __restrict__ gate_w,
    int* __restrict__ counts, int* __restrict__ row_token, float* __restrict__ row_weight,
    int* __restrict__ slot_e, int* __restrict__ slot_pos,
    unsigned short* __restrict__ x_bf)
{
    __shared__ float gsm[N_EXP * H_DIM];
    for (int i = threadIdx.x; i < N_EXP * H_DIM / 4; i += 256)
        ((float4*)gsm)[i] = ((const float4*)gate_w)[i];
    __syncthreads();

    const int wave = threadIdx.x >> 6;
    const int lane = threadIdx.x & 63;
    const int n = blockIdx.x * 4 + wave;
    if (n >= N_TOK) return;

    const float4* xrow = (const float4*)(x + (size_t)n * H_DIM);
    float4 xv[4];
#pragma unroll
    for (int i = 0; i < 4; i++) xv[i] = xrow[lane + 64 * i];

    // fused x -> bf16 (saves a pass in the convert kernel)
#pragma unroll
    for (int i = 0; i < 4; i++) {
        ushort4 b;
        b.x = f2bf(xv[i].x); b.y = f2bf(xv[i].y); b.z = f2bf(xv[i].z); b.w = f2bf(xv[i].w);
        *(ushort4*)(x_bf + (size_t)n * H_DIM + (lane + 64 * i) * 4) = b;
    }

    float logit[N_EXP];
#pragma unroll
    for (int e = 0; e < N_EXP; e++) {
        float p = 0.f;
#pragma unroll
        for (int i = 0; i < 4; i++) {
            const float4 g = ((const float4*)gsm)[e * 256 + lane + 64 * i];
            p += xv[i].x * g.x + xv[i].y * g.y + xv[i].z * g.z + xv[i].w * g.w;
        }
#pragma unroll
        for (int s = 32; s > 0; s >>= 1) p += __shfl_xor(p, s, 64);
        logit[e] = p;
    }

    if (lane == 0) {
        int e0 = 0; float l0 = logit[0];
#pragma unroll
        for (int e = 1; e < N_EXP; e++) if (logit[e] > l0) { l0 = logit[e]; e0 = e; }
        int e1 = -1; float l1 = -3.4e38f;
#pragma unroll
        for (int e = 0; e < N_EXP; e++) if (e != e0 && logit[e] > l1) { l1 = logit[e]; e1 = e; }
        float w0 = 1.f / (1.f + __expf(l1 - l0));
        float w1 = 1.f - w0;
        int p0 = atomicAdd(&counts[e0], 1);
        int p1 = atomicAdd(&counts[e1], 1);
        row_token[e0 * N_TOK + p0] = n;  row_weight[e0 * N_TOK + p0] = w0;
        row_token[e1 * N_TOK + p1] = n;  row_weight[e1 * N_TOK + p1] = w1;
        slot_e[n * 2 + 0] = e0;  slot_pos[n * 2 + 0] = p0;
        slot_e[n * 2 + 1] = e1;  slot_pos[n * 2 + 1] = p1;
    }
}

// ---------------- Scan: prefix offsets + compact live-tile table --------------
__global__ void scan_kernel(const int* __restrict__ counts, int* __restrict__ offsets,
                            int* __restrict__ tile_e, int* __restrict__ tile_m,
                            int* __restrict__ ntiles)
{
    if (threadIdx.x == 0 && blockIdx.x == 0) {
        int acc = 0, t = 0;
        for (int e = 0; e < N_EXP; e++) {
            offsets[e] = acc; acc += counts[e];
            const int nt = (counts[e] + 127) >> 7;
            for (int m = 0; m < nt; m++) { tile_e[t] = e; tile_m[t] = m; t++; }
        }
        *ntiles = t;
    }
}

// ---------------- Up GEMM (grouped, m97 structure, compact tiles) -------------
__global__ __launch_bounds__(256) void up_gemm_kernel(
    const unsigned short* __restrict__ x_bf, const unsigned short* __restrict__ w1_bf,
    const int* __restrict__ counts, const int* __restrict__ offsets,
    const int* __restrict__ tile_e, const int* __restrict__ tile_m,
    const int* __restrict__ ntiles,
    const int* __restrict__ row_token,
    unsigned short* __restrict__ act)
{
    const int slot = blockIdx.y;
    if (slot >= *ntiles) return;
    const int e = tile_e[slot];
    const int mTile = tile_m[slot];
    const int cnt = counts[e];
    const int fTile = blockIdx.x;
    const int off = offsets[e];

    __shared__ __align__(16) unsigned short As[128 * 64];
    __shared__ __align__(16) unsigned short Bs[128 * 64];

    const int tid = threadIdx.x;
    const int lane = tid & 63;
    const int wave = tid >> 6;
    const int wm = (wave >> 1) * 64, wn = (wave & 1) * 64;

    // staging geometry: 16 chunks of 1KB per tile; wave w owns chunks w*4..w*4+3.
    // chunk c covers rows c*8..c*8+7; lane l -> row c*8 + (l>>3), col elems (l&7)*8.
    const unsigned short* aSrc[4];
    const unsigned short* bSrc[4];
#pragma unroll
    for (int j = 0; j < 4; j++) {
        const int row_local = wave * 32 + j * 8 + (lane >> 3);
        const int pos = mTile * 128 + row_local;
        const int tok = row_token[e * N_TOK + min(pos, cnt - 1)];
        aSrc[j] = x_bf + (size_t)tok * H_DIM + (lane & 7) * 8;
        bSrc[j] = w1_bf + ((size_t)e * F_DIM + fTile * 128 + row_local) * H_DIM + (lane & 7) * 8;
    }

    f32x4 acc[4][4];
#pragma unroll
    for (int i = 0; i < 4; i++)
#pragma unroll
        for (int j = 0; j < 4; j++) acc[i][j] = (f32x4)(0.f);

    const int NKT = H_DIM / BK;   // 16
    for (int kt = 0; kt < NKT; kt++) {
        const int koff = kt * BK;
#pragma unroll
        for (int j = 0; j < 4; j++) {
            gload16(aSrc[j] + koff, As + (wave * 4 + j) * 512);
            gload16(bSrc[j] + koff, Bs + (wave * 4 + j) * 512);
        }
        __syncthreads();   // implicit vmcnt(0) drains the LDS-bound loads
#pragma unroll
        for (int kk = 0; kk < BK / 32; kk++) {
            const int kloc = kk * 32 + (lane >> 4) * 8;
            bf16x8 af[4], bfr[4];
#pragma unroll
            for (int i = 0; i < 4; i++)
                af[i] = *(const bf16x8*)(As + (wm + i * 16 + (lane & 15)) * 64 + kloc);
#pragma unroll
            for (int i = 0; i < 4; i++)
                bfr[i] = *(const bf16x8*)(Bs + (wn + i * 16 + (lane & 15)) * 64 + kloc);
#pragma unroll
            for (int i = 0; i < 4; i++)
#pragma unroll
                for (int j = 0; j < 4; j++)
                    acc[i][j] = __builtin_amdgcn_mfma_f32_16x16x32_bf16(af[i], bfr[j], acc[i][j], 0, 0, 0);
        }
        __syncthreads();
    }

    // epilogue: silu + bf16 store (C/D layout: col=lane&15, row=(lane>>4)*4+reg)
#pragma unroll
    for (int i = 0; i < 4; i++) {
        const int mrow = wm + i * 16 + ((lane >> 4) << 2);
#pragma unroll
        for (int r = 0; r < 4; r++) {
            const int m = mTile * 128 + mrow + r;
            if (m < cnt) {
#pragma unroll
                for (int j = 0; j < 4; j++) {
                    float v = acc[i][j][r];
                    float s = v / (1.f + __expf(-v));
                    int col = fTile * 128 + wn + j * 16 + (lane & 15);
                    act[(size_t)(off + m) * F_DIM + col] = f2bf(s);
                }
            }
        }
    }
}

// ---------------- Down GEMM (grouped, split-K=2, compact tiles) ---------------
__global__ __launch_bounds__(256) void down_gemm_kernel(
    const unsigned short* __restrict__ act, const unsigned short* __restrict__ w2_bf,
    const int* __restrict__ counts, const int* __restrict__ offsets,
    const int* __restrict__ tile_e, const int* __restrict__ tile_m,
    const int* __restrict__ ntiles,
    const float* __restrict__ row_weight,
    float* __restrict__ out_partial)   // [KSPLIT][NSLOT][H_DIM]
{
    const int slot = blockIdx.y;
    if (slot >= *ntiles) return;
    const int e = tile_e[slot];
    const int mTile = tile_m[slot];
    const int ks = blockIdx.z;
    const int cnt = counts[e];
    const int hTile = blockIdx.x;
    const int off = offsets[e];
    const int kbase = ks * KHALF;

    __shared__ __align__(16) unsigned short As[128 * 64];
    __shared__ __align__(16) unsigned short Bs[128 * 64];

    const int tid = threadIdx.x;
    const int lane = tid & 63;
    const int wave = tid >> 6;
    const int wm = (wave >> 1) * 64, wn = (wave & 1) * 64;

    const unsigned short* aSrc[4];
    const unsigned short* bSrc[4];
#pragma unroll
    for (int j = 0; j < 4; j++) {
        const int row_local = wave * 32 + j * 8 + (lane >> 3);
        const int slotRow = off + min(mTile * 128 + row_local, cnt - 1);
        aSrc[j] = act + (size_t)slotRow * F_DIM + kbase + (lane & 7) * 8;
        bSrc[j] = w2_bf + ((size_t)e * H_DIM + hTile * 128 + row_local) * F_DIM + kbase + (lane & 7) * 8;
    }

    f32x4 acc[4][4];
#pragma unroll
    for (int i = 0; i < 4; i++)
#pragma unroll
        for (int j = 0; j < 4; j++) acc[i][j] = (f32x4)(0.f);

    const int NKT = KHALF / BK;   // 22
    for (int kt = 0; kt < NKT; kt++) {
        const int koff = kt * BK;
#pragma unroll
        for (int j = 0; j < 4; j++) {
            gload16(aSrc[j] + koff, As + (wave * 4 + j) * 512);
            gload16(bSrc[j] + koff, Bs + (wave * 4 + j) * 512);
        }
        __syncthreads();
#pragma unroll
        for (int kk = 0; kk < BK / 32; kk++) {
            const int kloc = kk * 32 + (lane >> 4) * 8;
            bf16x8 af[4], bfr[4];
#pragma unroll
            for (int i = 0; i < 4; i++)
                af[i] = *(const bf16x8*)(As + (wm + i * 16 + (lane & 15)) * 64 + kloc);
#pragma unroll
            for (int i = 0; i < 4; i++)
                bfr[i] = *(const bf16x8*)(Bs + (wn + i * 16 + (lane & 15)) * 64 + kloc);
#pragma unroll
            for (int i = 0; i < 4; i++)
#pragma unroll
                for (int j = 0; j < 4; j++)
                    acc[i][j] = __builtin_amdgcn_mfma_f32_16x16x32_bf16(af[i], bfr[j], acc[i][j], 0, 0, 0);
        }
        __syncthreads();
    }

    float* obase = out_partial + (size_t)ks * NSLOT * H_DIM;
#pragma unroll
    for (int i = 0; i < 4; i++) {
        const int mrow = wm + i * 16 + ((lane >> 4) << 2);
#pragma unroll
        for (int r = 0; r < 4; r++) {
            const int m = mTile * 128 + mrow + r;
            if (m < cnt) {
                const float w = row_weight[e * N_TOK + m];
#pragma unroll
                for (int j = 0; j < 4; j++) {
                    int col = hTile * 128 + wn + j * 16 + (lane & 15);
                    obase[(size_t)(off + m) * H_DIM + col] = w * acc[i][j][r];
                }
            }
        }
    }
}

// ---------------- Combine: y[n] = sum over 2 slots x 2 K-splits ---------------
__global__ __launch_bounds__(256) void combine_kernel(
    const float* __restrict__ out_partial, const int* __restrict__ offsets,
    const int* __restrict__ slot_e, const int* __restrict__ slot_pos,
    float* __restrict__ out)
{
    const int n = blockIdx.x;
    const int r0 = offsets[slot_e[n * 2 + 0]] + slot_pos[n * 2 + 0];
    const int r1 = offsets[slot_e[n * 2 + 1]] + slot_pos[n * 2 + 1];
    const int t = threadIdx.x;
    const float* p0 = out_partial;
    const float* p1 = out_partial + (size_t)NSLOT * H_DIM;
    const float4 a = *(const float4*)(p0 + (size_t)r0 * H_DIM + t * 4);
    const float4 b = *(const float4*)(p1 + (size_t)r0 * H_DIM + t * 4);
    const float4 c = *(const float4*)(p0 + (size_t)r1 * H_DIM + t * 4);
    const float4 d = *(const float4*)(p1 + (size_t)r1 * H_DIM + t * 4);
    float4 s;
    s.x = (a.x + b.x) + (c.x + d.x);
    s.y = (a.y + b.y) + (c.y + d.y);
    s.z = (a.z + b.z) + (c.z + d.z);
    s.w = (a.w + b.w) + (c.w + d.w);
    *(float4*)(out + (size_t)n * H_DIM + t * 4) = s;
}

extern "C" void kernel_launch(void* const* d_in, const int* in_sizes, int n_in,
                              void* d_out, int out_size, void* d_ws, size_t ws_size,
                              hipStream_t stream) {
    const float* x      = (const float*)d_in[0];
    const float* gate_w = (const float*)d_in[1];
    const float* w1     = (const float*)d_in[2];
    const float* w2     = (const float*)d_in[3];
    float* out = (float*)d_out;

    char* ws = (char*)d_ws;
    size_t o = 0;
    auto alloc = [&](size_t bytes) -> void* {
        void* p = ws + o;
        o = (o + bytes + 255) & ~(size_t)255;
        return p;
    };
    int*   counts     = (int*)  alloc(N_EXP * sizeof(int));
    int*   offsets    = (int*)  alloc(N_EXP * sizeof(int));
    int*   tile_e     = (int*)  alloc(MAX_TILES * sizeof(int));
    int*   tile_m     = (int*)  alloc(MAX_TILES * sizeof(int));
    int*   ntiles     = (int*)  alloc(sizeof(int));
    int*   row_token  = (int*)  alloc((size_t)N_EXP * N_TOK * sizeof(int));
    float* row_weight = (float*)alloc((size_t)N_EXP * N_TOK * sizeof(float));
    int*   slot_e     = (int*)  alloc((size_t)N_TOK * 2 * sizeof(int));
    int*   slot_pos   = (int*)  alloc((size_t)N_TOK * 2 * sizeof(int));
    unsigned short* act = (unsigned short*)alloc((size_t)NSLOT * F_DIM * sizeof(unsigned short));
    float* out_partial = (float*)alloc((size_t)KSPLIT * NSLOT * H_DIM * sizeof(float));
    unsigned short* x_bf  = (unsigned short*)alloc((size_t)N_TOK * H_DIM * sizeof(unsigned short));
    unsigned short* w1_bf = (unsigned short*)alloc((size_t)N_EXP * F_DIM * H_DIM * sizeof(unsigned short));
    unsigned short* w2_bf = (unsigned short*)alloc((size_t)N_EXP * H_DIM * F_DIM * sizeof(unsigned short));

    hipMemsetAsync(counts, 0, N_EXP * sizeof(int), stream);

    router_kernel<<<N_TOK / 4, 256, 0, stream>>>(x, gate_w, counts, row_token, row_weight, slot_e, slot_pos, x_bf);
    scan_kernel<<<1, 64, 0, stream>>>(counts, offsets, tile_e, tile_m, ntiles);
    convert_w_kernel<<<4096, 256, 0, stream>>>(w1, w2, w1_bf, w2_bf);
    up_gemm_kernel<<<dim3(F_DIM / 128, MAX_TILES), 256, 0, stream>>>(
        x_bf, w1_bf, counts, offsets, tile_e, tile_m, ntiles, row_token, act);
    down_gemm_kernel<<<dim3(H_DIM / 128, MAX_TILES, KSPLIT), 256, 0, stream>>>(
        act, w2_bf, counts, offsets, tile_e, tile_m, ntiles, row_weight, out_partial);
    combine_kernel<<<N_TOK, 256, 0, stream>>>(out_partial, offsets, slot_e, slot_pos, out);
}